// Round 1
// baseline (215.437 us; speedup 1.0000x reference)
//
#include <hip/hip_runtime.h>

#define L_RES 1280
#define A_ATM 14
#define K_NB  30
#define FEAT  656
#define NCH   128
#define E_OUT_OFF (L_RES * K_NB * NCH)  // 4,915,200

// GEMM inner loop: NE edges, channel c, edges start at e0 in LDS feat.
template<int NE>
__device__ __forceinline__ void do_gemm(const float (*feat)[660],
                                        const float* __restrict__ W,
                                        int c, int e0, float* acc) {
    for (int k = 0; k < FEAT; k += 4) {
        float w0 = W[(k + 0) * NCH + c];
        float w1 = W[(k + 1) * NCH + c];
        float w2 = W[(k + 2) * NCH + c];
        float w3 = W[(k + 3) * NCH + c];
#pragma unroll
        for (int e = 0; e < NE; e++) {
            float4 f = *(const float4*)&feat[e0 + e][k];
            acc[e] = fmaf(f.x, w0, fmaf(f.y, w1, fmaf(f.z, w2, fmaf(f.w, w3, acc[e]))));
        }
    }
}

__global__ __launch_bounds__(256) void sidechain_feat_kernel(
    const float* __restrict__ X,
    const int*   __restrict__ ridx,
    const int*   __restrict__ clab,
    const int*   __restrict__ Eidx,
    const float* __restrict__ Wpos,
    const float* __restrict__ bpos,
    const float* __restrict__ Wedge,
    const float* __restrict__ gamma,
    const float* __restrict__ beta,
    float* __restrict__ out)
{
    __shared__ float feat[16][660];     // 15 edges x 656 features (row 15 unused pad)
    __shared__ float Epre[15][NCH];     // pre-LN GEMM output
    __shared__ float bbs[4][3];         // backbone atoms of residue i, order [1,0,2,3]
    __shared__ float scj[15][10][3];    // sidechain atoms of each neighbor
    __shared__ int   nbr[15];

    const int blk = blockIdx.x;         // 0..2559
    const int i   = blk >> 1;           // residue
    const int kh  = blk & 1;            // which half of the K=30 neighbors
    const int eg  = kh * 15;            // global edge offset within residue
    const int t   = threadIdx.x;

    if (t < 12) {
        const int perm[4] = {1, 0, 2, 3};
        int a = t / 3, c = t - a * 3;
        bbs[a][c] = X[(i * A_ATM + perm[a]) * 3 + c];
    }
    if (t < 15) nbr[t] = Eidx[i * K_NB + eg + t];
    __syncthreads();

    // ---- neighbor sidechain coords: 15 edges x 10 atoms x 3 = 450 loads ----
    for (int idx = t; idx < 450; idx += 256) {
        int e = idx / 30;
        int r = idx - e * 30;
        int a = r / 3, c = r - a * 3;
        scj[e][a][c] = X[(nbr[e] * A_ATM + 4 + a) * 3 + c];
    }
    // ---- positional features: 15 edges x 16 ----
    if (t < 240) {
        int e = t >> 4, c = t & 15;
        int j = nbr[e];
        int d;
        if (clab[i] == clab[j]) {
            int off = ridx[i] - ridx[j] + 32;
            d = off < 0 ? 0 : (off > 64 ? 64 : off);
        } else {
            d = 65;
        }
        feat[e][c] = Wpos[d * 16 + c] + bpos[c];
    }
    __syncthreads();

    // ---- RBF features: 15 edges x 40 atom pairs, 16 RBFs each ----
    for (int idx = t; idx < 600; idx += 256) {
        int e  = idx / 40;
        int p  = idx - e * 40;
        int ab = p / 10, as = p - ab * 10;
        float dx = bbs[ab][0] - scj[e][as][0];
        float dy = bbs[ab][1] - scj[e][as][1];
        float dz = bbs[ab][2] - scj[e][as][2];
        float dist = sqrtf(dx * dx + dy * dy + dz * dz + 1e-6f);
        bool self = (nbr[e] == i);  // AUTOREGRESSIVE: zero RBF on self edges
        float* dst = &feat[e][16 + p * 16];
#pragma unroll
        for (int q = 0; q < 4; q++) {
            float4 v;
            float m0 = 2.0f + (float)(4 * q + 0) * (20.0f / 15.0f);
            float m1 = 2.0f + (float)(4 * q + 1) * (20.0f / 15.0f);
            float m2 = 2.0f + (float)(4 * q + 2) * (20.0f / 15.0f);
            float m3 = 2.0f + (float)(4 * q + 3) * (20.0f / 15.0f);
            float a0 = (dist - m0) * 0.8f;
            float a1 = (dist - m1) * 0.8f;
            float a2 = (dist - m2) * 0.8f;
            float a3 = (dist - m3) * 0.8f;
            v.x = self ? 0.0f : __expf(-a0 * a0);
            v.y = self ? 0.0f : __expf(-a1 * a1);
            v.z = self ? 0.0f : __expf(-a2 * a2);
            v.w = self ? 0.0f : __expf(-a3 * a3);
            *(float4*)(dst + 4 * q) = v;
        }
    }
    __syncthreads();

    // ---- GEMM: (15 x 656) @ (656 x 128) ----
    // threads: c = t&127 channel; half = t>>7 picks edges [0,8) or [8,15).
    const int c    = t & 127;
    const int half = t >> 7;
    float acc[8];
#pragma unroll
    for (int e = 0; e < 8; e++) acc[e] = 0.0f;

    if (half == 0) {
        do_gemm<8>(feat, Wedge, c, 0, acc);
#pragma unroll
        for (int e = 0; e < 8; e++) Epre[e][c] = acc[e];
    } else {
        do_gemm<7>(feat, Wedge, c, 8, acc);
#pragma unroll
        for (int e = 0; e < 7; e++) Epre[8 + e][c] = acc[e];
    }
    __syncthreads();

    // ---- LayerNorm per edge over 128 channels + store ----
    const int wave = t >> 6;
    const int lane = t & 63;
    for (int e = wave; e < 15; e += 4) {
        float v0 = Epre[e][lane];
        float v1 = Epre[e][lane + 64];
        float s = v0 + v1;
        float q = v0 * v0 + v1 * v1;
#pragma unroll
        for (int off = 32; off > 0; off >>= 1) {
            s += __shfl_xor(s, off);
            q += __shfl_xor(q, off);
        }
        float mean = s * (1.0f / 128.0f);
        float var  = q * (1.0f / 128.0f) - mean * mean;
        float rstd = rsqrtf(var + 1e-5f);
        float* o = out + (size_t)(i * K_NB + eg + e) * NCH;
        o[lane]      = (v0 - mean) * rstd * gamma[lane]      + beta[lane];
        o[lane + 64] = (v1 - mean) * rstd * gamma[lane + 64] + beta[lane + 64];
    }

    // ---- E_idx passthrough (as float values) ----
    if (t < 15) out[E_OUT_OFF + i * K_NB + eg + t] = (float)nbr[t];
}

extern "C" void kernel_launch(void* const* d_in, const int* in_sizes, int n_in,
                              void* d_out, int out_size, void* d_ws, size_t ws_size,
                              hipStream_t stream) {
    const float* X     = (const float*)d_in[0];
    const int*   ridx  = (const int*)  d_in[1];
    const int*   clab  = (const int*)  d_in[2];
    const int*   Eidx  = (const int*)  d_in[3];
    // d_in[4] = atom_mask (unused by reference forward)
    const float* Wpos  = (const float*)d_in[5];
    const float* bpos  = (const float*)d_in[6];
    const float* Wedge = (const float*)d_in[7];
    const float* gamma = (const float*)d_in[8];
    const float* beta  = (const float*)d_in[9];
    float* out = (float*)d_out;

    dim3 grid(L_RES * 2);
    dim3 block(256);
    sidechain_feat_kernel<<<grid, block, 0, stream>>>(
        X, ridx, clab, Eidx, Wpos, bpos, Wedge, gamma, beta, out);
}

// Round 3
// 109.385 us; speedup vs baseline: 1.9695x; 1.9695x over previous
//
#include <hip/hip_runtime.h>

typedef short bf16x8 __attribute__((ext_vector_type(8)));
typedef float f32x4  __attribute__((ext_vector_type(4)));

#define L_RES 1280
#define A_ATM 14
#define K_NB  30
#define FEAT  656
#define KPAD  672          // 656 padded to 21*32 for the MFMA K-loop
#define NCH   128
#define AF_STRIDE 680      // bf16 elems per LDS A-row; 340 dwords -> 2-way bank aliasing (free)
#define E_OUT_OFF (L_RES * K_NB * NCH)

// fp32 -> bf16 round-to-nearest-even
__device__ __forceinline__ ushort f2bf(float x) {
    union { float f; unsigned u; } v; v.f = x;
    unsigned r = (v.u + 0x7fffu + ((v.u >> 16) & 1u)) >> 16;
    return (ushort)r;
}

// W_edge [656][128] fp32  ->  Wt [128][672] bf16 (k-padded with zeros)
__global__ __launch_bounds__(256) void wt_convert_kernel(const float* __restrict__ W,
                                                         ushort* __restrict__ Wt) {
    int idx = blockIdx.x * 256 + threadIdx.x;   // n*KPAD + k
    if (idx >= NCH * KPAD) return;
    int n = idx / KPAD, k = idx - n * KPAD;
    float v = (k < FEAT) ? W[k * NCH + n] : 0.0f;
    Wt[idx] = f2bf(v);
}

__global__ __launch_bounds__(256) void sidechain_feat_kernel(
    const float* __restrict__ X,
    const int*   __restrict__ ridx,
    const int*   __restrict__ clab,
    const int*   __restrict__ Eidx,
    const float* __restrict__ Wpos,
    const float* __restrict__ bpos,
    const ushort* __restrict__ Wt,     // bf16 [128][672]
    const float* __restrict__ gamma,
    const float* __restrict__ beta,
    float* __restrict__ out)
{
    // A-matrix (features, bf16) — later reused as fp32 C buffer for the LN.
    __shared__ __align__(16) ushort Af[32][AF_STRIDE];   // 43,520 B
    __shared__ float bbs[4][3];
    __shared__ float scj[K_NB][10][3];
    __shared__ int   nbr[K_NB];

    const int i = blockIdx.x;          // residue
    const int t = threadIdx.x;
    const int w = t >> 6;              // wave 0..3
    const int lane = t & 63;

    // ---- coords & neighbor indices ----
    if (t < 12) {
        const int perm[4] = {1, 0, 2, 3};
        int a = t / 3, c = t - a * 3;
        bbs[a][c] = X[(i * A_ATM + perm[a]) * 3 + c];
    }
    if (t < K_NB) nbr[t] = Eidx[i * K_NB + t];
    __syncthreads();

    for (int idx = t; idx < K_NB * 30; idx += 256) {     // 30 edges x 10 atoms x 3
        int e = idx / 30;
        int r = idx - e * 30;
        int a = r / 3, c = r - a * 3;
        scj[e][a][c] = X[(nbr[e] * A_ATM + 4 + a) * 3 + c];
    }

    // ---- positional features (cols 0..15): 30 edges x 16 = 480 items, MUST stride ----
    for (int idx = t; idx < K_NB * 16; idx += 256) {
        int e = idx >> 4, c = idx & 15;
        int j = nbr[e];
        int d;
        if (clab[i] == clab[j]) {
            int off = ridx[i] - ridx[j] + 32;
            d = off < 0 ? 0 : (off > 64 ? 64 : off);
        } else {
            d = 65;
        }
        Af[e][c] = f2bf(Wpos[d * 16 + c] + bpos[c]);
    }
    // ---- zero rows 30,31 entirely; zero k-pad cols 656..679 of rows 0..29 ----
    for (int idx = t; idx < 2 * AF_STRIDE; idx += 256)
        Af[30 + idx / AF_STRIDE][idx % AF_STRIDE] = 0;
    for (int idx = t; idx < 30 * 24; idx += 256)
        Af[idx / 24][FEAT + idx % 24] = 0;
    __syncthreads();

    // ---- RBF features: 30 edges x 40 pairs x 16 rbf, bf16-packed writes ----
    for (int idx = t; idx < K_NB * 40; idx += 256) {
        int e  = idx / 40;
        int p  = idx - e * 40;
        int ab = p / 10, as = p - ab * 10;
        float dx = bbs[ab][0] - scj[e][as][0];
        float dy = bbs[ab][1] - scj[e][as][1];
        float dz = bbs[ab][2] - scj[e][as][2];
        float dist = sqrtf(dx * dx + dy * dy + dz * dz + 1e-6f);
        bool self = (nbr[e] == i);     // AUTOREGRESSIVE: zero RBF on self edges
        unsigned* dst = (unsigned*)&Af[e][16 + p * 16];
#pragma unroll
        for (int q = 0; q < 8; q++) {
            float m0 = 2.0f + (float)(2 * q)     * (20.0f / 15.0f);
            float m1 = 2.0f + (float)(2 * q + 1) * (20.0f / 15.0f);
            float a0 = (dist - m0) * 0.8f;
            float a1 = (dist - m1) * 0.8f;
            float r0 = self ? 0.0f : __expf(-a0 * a0);
            float r1 = self ? 0.0f : __expf(-a1 * a1);
            dst[q] = (unsigned)f2bf(r0) | ((unsigned)f2bf(r1) << 16);
        }
    }
    __syncthreads();

    // ---- MFMA GEMM: C[32 x 128] = Af[32 x 672] @ Wt^T (bf16 -> fp32) ----
    // wave w owns N-tiles {2w, 2w+1}; both M-tiles.
    const int frow = lane & 15;        // fragment row / col-in-tile
    const int quad = lane >> 4;        // 0..3
    const ushort* A0p = &Af[frow][quad * 8];
    const ushort* A1p = &Af[16 + frow][quad * 8];
    const ushort* B0p = Wt + (size_t)((2 * w) * 16 + frow) * KPAD + quad * 8;
    const ushort* B1p = B0p + 16 * KPAD;

    f32x4 acc00 = {0.f,0.f,0.f,0.f}, acc01 = {0.f,0.f,0.f,0.f};
    f32x4 acc10 = {0.f,0.f,0.f,0.f}, acc11 = {0.f,0.f,0.f,0.f};

    bf16x8 a0 = *(const bf16x8*)(A0p);
    bf16x8 a1 = *(const bf16x8*)(A1p);
    bf16x8 b0 = *(const bf16x8*)(B0p);
    bf16x8 b1 = *(const bf16x8*)(B1p);

#pragma unroll
    for (int kb = 0; kb < KPAD; kb += 32) {
        bf16x8 ca0 = a0, ca1 = a1, cb0 = b0, cb1 = b1;
        if (kb + 32 < KPAD) {          // depth-1 prefetch; skip on last iter
            a0 = *(const bf16x8*)(A0p + kb + 32);
            a1 = *(const bf16x8*)(A1p + kb + 32);
            b0 = *(const bf16x8*)(B0p + kb + 32);
            b1 = *(const bf16x8*)(B1p + kb + 32);
        }
        acc00 = __builtin_amdgcn_mfma_f32_16x16x32_bf16(ca0, cb0, acc00, 0, 0, 0);
        acc01 = __builtin_amdgcn_mfma_f32_16x16x32_bf16(ca0, cb1, acc01, 0, 0, 0);
        acc10 = __builtin_amdgcn_mfma_f32_16x16x32_bf16(ca1, cb0, acc10, 0, 0, 0);
        acc11 = __builtin_amdgcn_mfma_f32_16x16x32_bf16(ca1, cb1, acc11, 0, 0, 0);
    }

    // all waves done reading Af before we overwrite it with fp32 C
    __syncthreads();
    float (*Epre)[132] = (float (*)[132])&Af[0][0];      // 32 x 132 fp32 = 16,896 B

    // C/D layout (verified m89/m91): col = lane&15, row = quad*4 + reg
#pragma unroll
    for (int r = 0; r < 4; r++) {
        int row0 = quad * 4 + r;
        Epre[row0][(2 * w)     * 16 + frow] = acc00[r];
        Epre[row0][(2 * w + 1) * 16 + frow] = acc01[r];
        Epre[16 + row0][(2 * w)     * 16 + frow] = acc10[r];
        Epre[16 + row0][(2 * w + 1) * 16 + frow] = acc11[r];
    }
    __syncthreads();

    // ---- LayerNorm per edge over 128 channels + store ----
    for (int e = w; e < K_NB; e += 4) {
        float v0 = Epre[e][lane];
        float v1 = Epre[e][lane + 64];
        float s = v0 + v1;
        float q = v0 * v0 + v1 * v1;
#pragma unroll
        for (int off = 32; off > 0; off >>= 1) {
            s += __shfl_xor(s, off);
            q += __shfl_xor(q, off);
        }
        float mean = s * (1.0f / 128.0f);
        float var  = q * (1.0f / 128.0f) - mean * mean;
        float rstd = rsqrtf(var + 1e-5f);
        float* o = out + (size_t)(i * K_NB + e) * NCH;
        o[lane]      = (v0 - mean) * rstd * gamma[lane]      + beta[lane];
        o[lane + 64] = (v1 - mean) * rstd * gamma[lane + 64] + beta[lane + 64];
    }

    // ---- E_idx passthrough (as float) ----
    if (t < K_NB) out[E_OUT_OFF + i * K_NB + t] = (float)nbr[t];
}

extern "C" void kernel_launch(void* const* d_in, const int* in_sizes, int n_in,
                              void* d_out, int out_size, void* d_ws, size_t ws_size,
                              hipStream_t stream) {
    const float* X     = (const float*)d_in[0];
    const int*   ridx  = (const int*)  d_in[1];
    const int*   clab  = (const int*)  d_in[2];
    const int*   Eidx  = (const int*)  d_in[3];
    // d_in[4] = atom_mask (unused by reference forward)
    const float* Wpos  = (const float*)d_in[5];
    const float* bpos  = (const float*)d_in[6];
    const float* Wedge = (const float*)d_in[7];
    const float* gamma = (const float*)d_in[8];
    const float* beta  = (const float*)d_in[9];
    float* out = (float*)d_out;

    ushort* Wt = (ushort*)d_ws;   // 128*672*2 = 172,032 B

    wt_convert_kernel<<<(NCH * KPAD + 255) / 256, 256, 0, stream>>>(Wedge, Wt);
    sidechain_feat_kernel<<<L_RES, 256, 0, stream>>>(
        X, ridx, clab, Eidx, Wpos, bpos, Wt, gamma, beta, out);
}